// Round 8
// baseline (629.030 us; speedup 1.0000x reference)
//
#include <hip/hip_runtime.h>

#define NSHOTS 4
#define NT     512
#define NZ     256
#define NX     256
#define NRECS  128

static constexpr float DTf    = 0.001f;
static constexpr float INVDH2 = 1.0f / (10.0f * 10.0f);

#define KSTEPS 16                 // fused steps per phase
#define TZI    16                 // interior tile z
#define TXI    32                 // interior tile x
#define EXTZ   48                 // TZI + 2*KSTEPS
#define RPT    12                 // ext rows per thread (EXTZ / 4 waves)
#define NWAVES 4
#define BLOCK  256
#define NWG    (NSHOTS * 128)     // 512 WGs -> 2 per CU (stall hiding)
#define NPHASE (NT / KSTEPS)      // 32
#define LSTRIDE 32                // dwords between flags (128 B)
#define FCNT   (NSHOTS * NZ * NX)

// lane i <- lane i-1 (left x-neighbor); lane 0 gets 0 (matches zero pad)
__device__ __forceinline__ float nbr_left(float v) {
  return __int_as_float(__builtin_amdgcn_update_dpp(
      0, __float_as_int(v), 0x138 /*WAVE_SHR1*/, 0xf, 0xf, false));
}
// lane i <- lane i+1 (right x-neighbor); lane 63 gets 0
__device__ __forceinline__ float nbr_right(float v) {
  return __int_as_float(__builtin_amdgcn_update_dpp(
      0, __float_as_int(v), 0x130 /*WAVE_SHL1*/, 0xf, 0xf, false));
}

// LLC-coherent (cross-XCD) access: agent-scope relaxed -> sc0 sc1.
__device__ __forceinline__ float gload(const float* p) {
  return __hip_atomic_load(p, __ATOMIC_RELAXED, __HIP_MEMORY_SCOPE_AGENT);
}
__device__ __forceinline__ void gstore(float* p, float v) {
  __hip_atomic_store(p, v, __ATOMIC_RELAXED, __HIP_MEMORY_SCOPE_AGENT);
}
__device__ __forceinline__ unsigned fload(const unsigned* p) {
  return __hip_atomic_load(p, __ATOMIC_RELAXED, __HIP_MEMORY_SCOPE_AGENT);
}
__device__ __forceinline__ void fstore(unsigned* p, unsigned v) {
  __hip_atomic_store(p, v, __ATOMIC_RELAXED, __HIP_MEMORY_SCOPE_AGENT);
}

__global__ __launch_bounds__(BLOCK, 4) void wave_p2p_half(
    float* __restrict__ f0c, float* __restrict__ f0p,   // pair 0 (even-phase writes)
    float* __restrict__ f1c, float* __restrict__ f1p,   // pair 1 (odd-phase writes)
    const float* __restrict__ vp, const float* __restrict__ xwav,
    const int* __restrict__ src_z, const int* __restrict__ src_x,
    const int* __restrict__ rec_z, const int* __restrict__ rec_x,
    float* __restrict__ out,                            // [NSHOTS*NT*NRECS]
    unsigned* __restrict__ bar)                         // wFlag[NWG], rFlag[NWG] @128B
{
  const int bid  = blockIdx.x;
  const int s    = bid >> 7;          // 128 tiles per shot
  const int tz   = (bid >> 3) & 15;   // 16 z-tiles
  const int tx   = bid & 7;           // 8 x-tiles
  const int tid  = threadIdx.x;
  const int w    = tid >> 6;          // wave 0..3
  const int lane = tid & 63;

  const int gz0 = tz * TZI - KSTEPS;
  const int gx0 = tx * TXI - KSTEPS;
  const int gx  = gx0 + lane;
  const int zb  = w * RPT;

  __shared__ float haloTop[2][NWAVES][64];
  __shared__ float haloBot[2][NWAVES][64];
  __shared__ float recTile[2][TZI][TXI + 1];
  __shared__ int   cntS;
  __shared__ int   lzA[NRECS], lxA[NRECS];
  __shared__ unsigned pkA[NRECS];

  // ---- prologue: receiver compaction + per-thread masks ----
  if (tid == 0) cntS = 0;
  __syncthreads();
  if (tid < NRECS) {
    const int lz = rec_z[s * NRECS + tid] - tz * TZI;
    const int lx = rec_x[s * NRECS + tid] - tx * TXI;
    lzA[tid] = lz; lxA[tid] = lx;
    if ((unsigned)lz < (unsigned)TZI && (unsigned)lx < (unsigned)TXI) {
      const int k = atomicAdd(&cntS, 1);
      pkA[k] = (unsigned)tid | ((unsigned)lz << 8) | ((unsigned)lx << 16);
    }
  }
  __syncthreads();
  const int nRec = cntS;
  int myR = 0, myLz = 0, myLx = 0;
  if (tid < nRec) {
    const unsigned p = pkA[tid];
    myR = p & 255; myLz = (p >> 8) & 31; myLx = (p >> 16) & 31;
  }
  // receiver-cell bits + interior(writeback) bits, per row i: ext z = zb+i
  unsigned recMask = 0, wbBits = 0;
  {
    const bool laneIn = (lane >= KSTEPS && lane < KSTEPS + TXI);
    #pragma unroll
    for (int i = 0; i < RPT; ++i) {
      const int extz = zb + i;
      if (laneIn && extz >= KSTEPS && extz < KSTEPS + TZI) wbBits |= 1u << i;
    }
    for (int r = 0; r < NRECS; ++r) {
      const int lz = lzA[r], lx = lxA[r];
      if ((unsigned)lz < (unsigned)TZI && (unsigned)lx < (unsigned)TXI &&
          lx + KSTEPS == lane) {
        const int e = lz + KSTEPS - zb;
        if ((unsigned)e < (unsigned)RPT) recMask |= 1u << e;
      }
    }
  }
  const int ilxc = lane - KSTEPS;   // interior x coord (valid when wbBits row)

  // neighbor bid for flag lanes (tid<8 -> 8 surrounding tiles, same shot)
  int nb = -1;
  if (tid < 8) {
    const int k  = (tid < 4) ? tid : tid + 1;   // skip center of 3x3
    const int dz = k / 3 - 1, dx = k % 3 - 1;
    const int qz = tz + dz, qx = tx + dx;
    if ((unsigned)qz < 16u && (unsigned)qx < 8u)
      nb = (s << 7) | (qz << 3) | qx;
  }
  unsigned* wF = bar;
  unsigned* rF = bar + (size_t)NWG * LSTRIDE;

  auto pollGE = [&](unsigned* base, unsigned target) {
    if (nb >= 0) {
      while (fload(base + (size_t)nb * LSTRIDE) < target)
        __builtin_amdgcn_s_sleep(1);
    }
  };

  // source mask
  const int slz = src_z[s] - gz0;
  const int slx = src_x[s] - gx0;
  const bool srcMine = (slx == lane) && ((unsigned)(slz - zb) < (unsigned)RPT);
  const int  srcI = slz - zb;
  float srcM[RPT];
  #pragma unroll
  for (int i = 0; i < RPT; ++i) srcM[i] = (srcMine && srcI == i) ? 1.0f : 0.0f;

  // phase-invariant per-row addresses/validity + c2 in registers
  const bool xok = (unsigned)gx < (unsigned)NX;
  int   offRow[RPT];
  bool  okRow[RPT];
  float a[RPT], b[RPT], c2[RPT];
  #pragma unroll
  for (int i = 0; i < RPT; ++i) {
    const int gz = gz0 + zb + i;
    const bool ok = xok && ((unsigned)gz < (unsigned)NZ);
    okRow[i]  = ok;
    offRow[i] = ok ? ((s * NZ + gz) * NX + gx) : 0;
    float v = ok ? vp[gz * NX + gx] : 0.0f;
    v *= DTf;
    c2[i] = v * v * INVDH2;
    a[i] = 0.0f; b[i] = 0.0f;
  }

  #pragma unroll 1
  for (int ph = 0; ph < NPHASE; ++ph) {
    const int t0 = ph * KSTEPS;

    if (ph > 0) {
      pollGE(wF, (unsigned)ph);          // 8 neighbors finished phase ph-1
      __syncthreads();
      const float* rc = (ph & 1) ? f0c : f1c;
      const float* rp = (ph & 1) ? f0p : f1p;
      #pragma unroll
      for (int i = 0; i < RPT; ++i) {
        a[i] = okRow[i] ? gload(rc + offRow[i]) : 0.0f;
        b[i] = okRow[i] ? gload(rp + offRow[i]) : 0.0f;
      }
      __builtin_amdgcn_s_waitcnt(0);     // my reload actually read memory
      __syncthreads();
      if (tid == 0) fstore(rF + (size_t)bid * LSTRIDE, (unsigned)ph);
    }

    // 16 source amps via 4 vector loads (t0 is 64B-aligned into xwav row)
    float amp[KSTEPS];
    {
      const float4* xw4 = (const float4*)(xwav + s * NT + t0);
      #pragma unroll
      for (int q = 0; q < KSTEPS / 4; ++q) {
        const float4 v = xw4[q];
        amp[4 * q + 0] = (v.x * DTf) * DTf;
        amp[4 * q + 1] = (v.y * DTf) * DTf;
        amp[4 * q + 2] = (v.z * DTf) * DTf;
        amp[4 * q + 3] = (v.w * DTf) * DTf;
      }
    }

    float recv[KSTEPS];

    auto do_step = [&](float (&cur)[RPT], float (&nxt)[RPT], int tau) {
      const int pb = tau & 1;
      haloTop[pb][w][lane] = cur[0];
      haloBot[pb][w][lane] = cur[RPT - 1];
      __syncthreads();
      if (tau > 0 && tid < nRec) recv[tau - 1] = recTile[1 - pb][myLz][myLx];
      const float up0 = (w > 0)          ? haloBot[pb][w - 1][lane] : 0.0f;
      const float dnL = (w < NWAVES - 1) ? haloTop[pb][w + 1][lane] : 0.0f;
      #pragma unroll
      for (int i = 0; i < RPT; ++i) {
        const float c  = cur[i];
        const float up = (i == 0)       ? up0 : cur[i - 1];
        const float dn = (i == RPT - 1) ? dnL : cur[i + 1];
        const float lf = nbr_left(c);
        const float rt = nbr_right(c);
        const float sum = (up + dn) + (lf + rt);
        const float lap = __builtin_fmaf(-4.0f, c, sum);
        float v = __builtin_fmaf(2.0f, c, -nxt[i]);
        v = __builtin_fmaf(c2[i], lap, v);
        v = __builtin_fmaf(srcM[i], amp[tau], v);
        nxt[i] = v;
      }
      if (recMask) {
        #pragma unroll
        for (int i = 0; i < RPT; ++i)
          if (recMask & (1u << i)) recTile[pb][zb + i - KSTEPS][ilxc] = nxt[i];
      }
    };

    #pragma unroll
    for (int h = 0; h < KSTEPS / 2; ++h) {
      do_step(a, b, 2 * h);
      do_step(b, a, 2 * h + 1);
    }

    // neighbors consumed the pair we're about to overwrite
    if (ph >= 2 && ph != NPHASE - 1) pollGE(rF, (unsigned)(ph - 1));
    __syncthreads();   // recTile[1] ready + overwrite permission WG-wide
    if (tid < nRec) recv[KSTEPS - 1] = recTile[1][myLz][myLx];

    // receiver flush (normal cached stores; read only after kernel end)
    if (tid < nRec) {
      #pragma unroll
      for (int t = 0; t < KSTEPS; ++t)
        out[(s * NT + (t0 + t)) * NRECS + myR] = recv[t];
    }

    if (ph != NPHASE - 1) {
      // interior writeback (LLC-coherent)
      float* wc = (ph & 1) ? f1c : f0c;
      float* wp = (ph & 1) ? f1p : f0p;
      if (wbBits) {
        #pragma unroll
        for (int i = 0; i < RPT; ++i) {
          if (wbBits & (1u << i)) {
            gstore(wc + offRow[i], a[i]);
            gstore(wp + offRow[i], b[i]);
          }
        }
      }
      __builtin_amdgcn_s_waitcnt(0);   // stores ack'd at LLC (per wave)
      __syncthreads();                 // whole WG drained
      if (tid == 0) fstore(wF + (size_t)bid * LSTRIDE, (unsigned)(ph + 1));
    }
  }
}

extern "C" void kernel_launch(void* const* d_in, const int* in_sizes, int n_in,
                              void* d_out, int out_size, void* d_ws, size_t ws_size,
                              hipStream_t stream) {
  const float* x     = (const float*)d_in[0];
  const float* vp    = (const float*)d_in[1];
  const int*   src_z = (const int*)d_in[2];
  const int*   src_x = (const int*)d_in[3];
  const int*   rec_z = (const int*)d_in[4];
  const int*   rec_x = (const int*)d_in[5];
  float* out = (float*)d_out;

  float* ws = (float*)d_ws;
  const size_t F = (size_t)FCNT;
  float* f0c = ws;
  float* f0p = ws + F;
  float* f1c = ws + 2 * F;
  float* f1p = ws + 3 * F;
  unsigned* bar = (unsigned*)(ws + 4 * F);

  // zero the p2p flags (wFlag + rFlag, 128B-strided)
  hipMemsetAsync(bar, 0, 2 * (size_t)NWG * LSTRIDE * sizeof(unsigned), stream);

  wave_p2p_half<<<dim3(NWG), dim3(BLOCK), 0, stream>>>(
      f0c, f0p, f1c, f1p, vp, x, src_z, src_x, rec_z, rec_x, out, bar);
}

// Round 9
// 554.467 us; speedup vs baseline: 1.1345x; 1.1345x over previous
//
#include <hip/hip_runtime.h>
#include <type_traits>

#define NSHOTS 4
#define NT     512
#define NZ     256
#define NX     256
#define NRECS  128

static constexpr float DTf    = 0.001f;
static constexpr float INVDH2 = 1.0f / (10.0f * 10.0f);

#define KSTEPS 16                 // fused steps per phase
#define TILE   32                 // interior tile edge
#define EXT    64                 // TILE + 2*KSTEPS
#define RPT    8                  // ext rows per thread
#define NWAVES 8
#define BLOCK  512
#define NWG    (NSHOTS * 64)      // 256 WGs, one per CU (co-resident)
#define NPHASE (NT / KSTEPS)      // 32

// lane i <- lane i-1 (left x-neighbor); OOB lane 0 reads 0 (bound_ctrl=1)
__device__ __forceinline__ float nbr_left(float v) {
  return __int_as_float(__builtin_amdgcn_update_dpp(
      0, __float_as_int(v), 0x138 /*WAVE_SHR1*/, 0xf, 0xf, true));
}
// lane i <- lane i+1 (right x-neighbor); OOB lane 63 reads 0
__device__ __forceinline__ float nbr_right(float v) {
  return __int_as_float(__builtin_amdgcn_update_dpp(
      0, __float_as_int(v), 0x130 /*WAVE_SHL1*/, 0xf, 0xf, true));
}

// LLC-coherent (cross-XCD) access: agent-scope relaxed -> sc0 sc1.
__device__ __forceinline__ float gload(const float* p) {
  return __hip_atomic_load(p, __ATOMIC_RELAXED, __HIP_MEMORY_SCOPE_AGENT);
}
__device__ __forceinline__ void gstore(float* p, float v) {
  __hip_atomic_store(p, v, __ATOMIC_RELAXED, __HIP_MEMORY_SCOPE_AGENT);
}
__device__ __forceinline__ unsigned fload(const unsigned* p) {
  return __hip_atomic_load(p, __ATOMIC_RELAXED, __HIP_MEMORY_SCOPE_AGENT);
}
__device__ __forceinline__ void fstore(unsigned* p, unsigned v) {
  __hip_atomic_store(p, v, __ATOMIC_RELAXED, __HIP_MEMORY_SCOPE_AGENT);
}

// Per-WAVE boundary flags: one 128B line per WG holds its 8 wave-flags
// (4B stride). Each polling wave checks all 8 neighbors x 8 waves = 64
// flags with one load per lane -> no WG-wide barrier in the boundary path.
__global__ __launch_bounds__(BLOCK, 4) void wave_p2pw(
    float* __restrict__ f0c, float* __restrict__ f0p,   // pair 0 (even-phase writes)
    float* __restrict__ f1c, float* __restrict__ f1p,   // pair 1 (odd-phase writes)
    const float* __restrict__ vp, const float* __restrict__ xwav,
    const int* __restrict__ src_z, const int* __restrict__ src_x,
    const int* __restrict__ rec_z, const int* __restrict__ rec_x,
    float* __restrict__ out,                            // [NSHOTS*NT*NRECS]
    unsigned* __restrict__ bar)                         // wFw[NWG*32], rFw[NWG*32]
{
  const int bid  = blockIdx.x;
  const int s    = bid >> 6;
  const int tz   = (bid >> 3) & 7;
  const int tx   = bid & 7;
  const int tid  = threadIdx.x;
  const int w    = tid >> 6;
  const int lane = tid & 63;

  const int gz0 = tz * TILE - KSTEPS;
  const int gx0 = tx * TILE - KSTEPS;
  const int gx  = gx0 + lane;
  const int zb  = w * RPT;

  __shared__ float haloTop[2][NWAVES][64];
  __shared__ float haloBot[2][NWAVES][64];
  __shared__ float recTile[2][TILE][TILE + 1];
  __shared__ int   cntS;
  __shared__ int   lzA[NRECS], lxA[NRECS];
  __shared__ unsigned pkA[NRECS];

  // ---- prologue: receiver compaction + masks ----
  if (tid == 0) cntS = 0;
  __syncthreads();
  if (tid < NRECS) {
    const int lz = rec_z[s * NRECS + tid] - tz * TILE;
    const int lx = rec_x[s * NRECS + tid] - tx * TILE;
    lzA[tid] = lz; lxA[tid] = lx;
    if ((unsigned)lz < (unsigned)TILE && (unsigned)lx < (unsigned)TILE) {
      const int k = atomicAdd(&cntS, 1);
      pkA[k] = (unsigned)tid | ((unsigned)lz << 8) | ((unsigned)lx << 16);
    }
  }
  __syncthreads();
  const int nRec = cntS;
  int myR = 0, myLz = 0, myLx = 0;
  if (tid < nRec) {
    const unsigned p = pkA[tid];
    myR = p & 255; myLz = (p >> 8) & 31; myLx = (p >> 16) & 31;
  }
  const bool wbRow = (w >= 2 && w < 6) && (lane >= KSTEPS && lane < KSTEPS + TILE);
  const int  ilz   = (w - 2) * RPT;
  const int  ilx   = lane - KSTEPS;
  unsigned recMask = 0;
  if (wbRow) {
    for (int r = 0; r < NRECS; ++r)
      if (lxA[r] == ilx && (unsigned)(lzA[r] - ilz) < (unsigned)RPT)
        recMask |= 1u << (lzA[r] - ilz);
  }

  // per-lane neighbor-wave flag mapping: lane -> (neighbor n=lane>>3, wave lane&7)
  const int nn  = lane >> 3;
  const int kk  = (nn < 4) ? nn : nn + 1;     // skip center of 3x3
  const int qz  = tz + (kk / 3 - 1);
  const int qx  = tx + (kk % 3 - 1);
  const bool nbValid = ((unsigned)qz < 8u) && ((unsigned)qx < 8u);
  const int flagIdx = ((((s << 6) | (qz << 3) | qx) << 5) | (lane & 7));
  unsigned* wFw = bar;
  unsigned* rFw = bar + (size_t)NWG * 32;

  auto pollGE = [&](unsigned* base, unsigned target) {
    if (nbValid) {
      while (fload(base + flagIdx) < target)
        __builtin_amdgcn_s_sleep(1);
    }
  };

  // source mask (ext-region coverage keeps halo values valid)
  const int slz = src_z[s] - gz0;
  const int slx = src_x[s] - gx0;
  const bool srcInExt = ((unsigned)slz < (unsigned)EXT) && ((unsigned)slx < (unsigned)EXT);
  const bool srcMine = (slx == lane) && ((unsigned)(slz - zb) < (unsigned)RPT);
  const int  srcI = slz - zb;
  float srcM[RPT];
  #pragma unroll
  for (int i = 0; i < RPT; ++i) srcM[i] = (srcMine && srcI == i) ? 1.0f : 0.0f;

  // phase-invariant per-row addresses/validity + c2 in registers
  const bool xok = (unsigned)gx < (unsigned)NX;
  int   offRow[RPT];
  bool  okRow[RPT];
  float a[RPT], b[RPT], c2[RPT];
  #pragma unroll
  for (int i = 0; i < RPT; ++i) {
    const int gz = gz0 + zb + i;
    const bool ok = xok && ((unsigned)gz < (unsigned)NZ);
    okRow[i]  = ok;
    offRow[i] = ok ? ((s * NZ + gz) * NX + gx) : 0;
    float v = ok ? vp[gz * NX + gx] : 0.0f;
    v *= DTf;
    c2[i] = v * v * INVDH2;
    a[i] = 0.0f; b[i] = 0.0f;
  }

  #pragma unroll 1
  for (int ph = 0; ph < NPHASE; ++ph) {
    const int t0 = ph * KSTEPS;

    if (ph > 0) {
      // per-wave: all 64 neighbor-wave write-flags at phase ph
      pollGE(wFw, (unsigned)ph);
      // reload ghost region (interior threads keep a,b in registers)
      const float* rc = (ph & 1) ? f0c : f1c;
      const float* rp = (ph & 1) ? f0p : f1p;
      if (!wbRow) {
        #pragma unroll
        for (int i = 0; i < RPT; ++i) {
          a[i] = okRow[i] ? gload(rc + offRow[i]) : 0.0f;
          b[i] = okRow[i] ? gload(rp + offRow[i]) : 0.0f;
        }
      }
      __builtin_amdgcn_s_waitcnt(0);     // this wave's reload complete
      if (lane == 0) fstore(rFw + ((bid << 5) | w), (unsigned)ph);
    }

    // 16 source amps via 4 vector loads (t0 is 64B-aligned into xwav row)
    float amp[KSTEPS];
    {
      const float4* xw4 = (const float4*)(xwav + s * NT + t0);
      #pragma unroll
      for (int q = 0; q < KSTEPS / 4; ++q) {
        const float4 v = xw4[q];
        amp[4 * q + 0] = (v.x * DTf) * DTf;
        amp[4 * q + 1] = (v.y * DTf) * DTf;
        amp[4 * q + 2] = (v.z * DTf) * DTf;
        amp[4 * q + 3] = (v.w * DTf) * DTf;
      }
    }

    float recv[KSTEPS];

    auto run_steps = [&](auto srcc) {
      auto do_step = [&](float (&cur)[RPT], float (&nxt)[RPT], int tau) {
        const int pb = tau & 1;
        haloTop[pb][w][lane] = cur[0];
        haloBot[pb][w][lane] = cur[RPT - 1];
        __syncthreads();
        if (tau > 0 && tid < nRec) recv[tau - 1] = recTile[1 - pb][myLz][myLx];
        const float up0 = (w > 0)          ? haloBot[pb][w - 1][lane] : 0.0f;
        const float dn7 = (w < NWAVES - 1) ? haloTop[pb][w + 1][lane] : 0.0f;
        #pragma unroll
        for (int i = 0; i < RPT; ++i) {
          const float c  = cur[i];
          const float up = (i == 0)       ? up0 : cur[i - 1];
          const float dn = (i == RPT - 1) ? dn7 : cur[i + 1];
          const float lf = nbr_left(c);
          const float rt = nbr_right(c);
          const float sum = (up + dn) + (lf + rt);
          const float lap = __builtin_fmaf(-4.0f, c, sum);
          float v = __builtin_fmaf(2.0f, c, -nxt[i]);
          v = __builtin_fmaf(c2[i], lap, v);
          if constexpr (decltype(srcc)::value) {
            v = __builtin_fmaf(srcM[i], amp[tau], v);
          }
          nxt[i] = v;
        }
        if (recMask) {
          #pragma unroll
          for (int i = 0; i < RPT; ++i)
            if (recMask & (1u << i)) recTile[pb][ilz + i][ilx] = nxt[i];
        }
      };
      #pragma unroll
      for (int h = 0; h < KSTEPS / 2; ++h) {
        do_step(a, b, 2 * h);
        do_step(b, a, 2 * h + 1);
      }
    };
    if (srcInExt) run_steps(std::true_type{});
    else          run_steps(std::false_type{});

    __syncthreads();   // recTile[1] complete WG-wide
    if (tid < nRec) recv[KSTEPS - 1] = recTile[1][myLz][myLx];

    // receiver flush (normal cached stores; read only after kernel end)
    if (tid < nRec) {
      #pragma unroll
      for (int t = 0; t < KSTEPS; ++t)
        out[(s * NT + (t0 + t)) * NRECS + myR] = recv[t];
    }

    if (ph != NPHASE - 1) {
      // per-wave: neighbors consumed the slab we're about to overwrite
      if (ph >= 2) pollGE(rFw, (unsigned)(ph - 1));
      // interior writeback (LLC-coherent)
      float* wc = (ph & 1) ? f1c : f0c;
      float* wp = (ph & 1) ? f1p : f0p;
      if (wbRow) {
        #pragma unroll
        for (int i = 0; i < RPT; ++i) {
          gstore(wc + offRow[i], a[i]);
          gstore(wp + offRow[i], b[i]);
        }
      }
      __builtin_amdgcn_s_waitcnt(0);   // this wave's stores ack'd at LLC
      if (lane == 0) fstore(wFw + ((bid << 5) | w), (unsigned)(ph + 1));
    }
  }
}

extern "C" void kernel_launch(void* const* d_in, const int* in_sizes, int n_in,
                              void* d_out, int out_size, void* d_ws, size_t ws_size,
                              hipStream_t stream) {
  const float* x     = (const float*)d_in[0];
  const float* vp    = (const float*)d_in[1];
  const int*   src_z = (const int*)d_in[2];
  const int*   src_x = (const int*)d_in[3];
  const int*   rec_z = (const int*)d_in[4];
  const int*   rec_x = (const int*)d_in[5];
  float* out = (float*)d_out;

  float* ws = (float*)d_ws;
  const size_t F = (size_t)NSHOTS * NZ * NX;
  float* f0c = ws;
  float* f0p = ws + F;
  float* f1c = ws + 2 * F;
  float* f1p = ws + 3 * F;
  unsigned* bar = (unsigned*)(ws + 4 * F);

  // zero the per-wave p2p flags (wFw + rFw, 32 dwords per WG each)
  hipMemsetAsync(bar, 0, 2 * (size_t)NWG * 32 * sizeof(unsigned), stream);

  wave_p2pw<<<dim3(NWG), dim3(BLOCK), 0, stream>>>(
      f0c, f0p, f1c, f1p, vp, x, src_z, src_x, rec_z, rec_x, out, bar);
}

// Round 10
// 323.895 us; speedup vs baseline: 1.9421x; 1.7119x over previous
//
#include <hip/hip_runtime.h>

#define NSHOTS 4
#define NT     512
#define NZ     256
#define NX     256
#define NRECS  128

static constexpr float DTf    = 0.001f;
static constexpr float INVDH2 = 1.0f / (10.0f * 10.0f);

#define KSTEPS 16                 // fused steps per phase
#define TILE   32                 // interior tile edge
#define RPT    8                  // ext rows per thread (4 float2 pairs)
#define NPAIRS 4                  // RPT/2
#define NWAVES 8
#define BLOCK  512
#define NWG    (NSHOTS * 64)      // 256 WGs, one per CU (co-resident)
#define NPHASE (NT / KSTEPS)      // 32
#define LSTRIDE 32                // dwords between flags (128 B)

typedef float v2f __attribute__((ext_vector_type(2)));

// lane i <- lane i-1 (left x-neighbor); OOB lane 0 reads 0 (bound_ctrl=1,
// matches zero pad; correctness verified R9)
__device__ __forceinline__ float nbr_left(float v) {
  return __int_as_float(__builtin_amdgcn_update_dpp(
      0, __float_as_int(v), 0x138 /*WAVE_SHR1*/, 0xf, 0xf, true));
}
// lane i <- lane i+1 (right x-neighbor); OOB lane 63 reads 0
__device__ __forceinline__ float nbr_right(float v) {
  return __int_as_float(__builtin_amdgcn_update_dpp(
      0, __float_as_int(v), 0x130 /*WAVE_SHL1*/, 0xf, 0xf, true));
}

// LLC-coherent (cross-XCD) access: agent-scope relaxed -> sc0 sc1.
__device__ __forceinline__ float gload(const float* p) {
  return __hip_atomic_load(p, __ATOMIC_RELAXED, __HIP_MEMORY_SCOPE_AGENT);
}
__device__ __forceinline__ void gstore(float* p, float v) {
  __hip_atomic_store(p, v, __ATOMIC_RELAXED, __HIP_MEMORY_SCOPE_AGENT);
}
__device__ __forceinline__ unsigned fload(const unsigned* p) {
  return __hip_atomic_load(p, __ATOMIC_RELAXED, __HIP_MEMORY_SCOPE_AGENT);
}
__device__ __forceinline__ void fstore(unsigned* p, unsigned v) {
  __hip_atomic_store(p, v, __ATOMIC_RELAXED, __HIP_MEMORY_SCOPE_AGENT);
}

__global__ __launch_bounds__(BLOCK, 4) void wave_pk(
    float* __restrict__ f0c, float* __restrict__ f0p,   // pair 0 (even-phase writes)
    float* __restrict__ f1c, float* __restrict__ f1p,   // pair 1 (odd-phase writes)
    const float* __restrict__ vp, const float* __restrict__ xwav,
    const int* __restrict__ src_z, const int* __restrict__ src_x,
    const int* __restrict__ rec_z, const int* __restrict__ rec_x,
    float* __restrict__ out,                            // [NSHOTS*NT*NRECS]
    unsigned* __restrict__ bar)                         // wFlag[NWG], rFlag[NWG] @128B
{
  const int bid  = blockIdx.x;
  const int s    = bid >> 6;
  const int tz   = (bid >> 3) & 7;
  const int tx   = bid & 7;
  const int tid  = threadIdx.x;
  const int w    = tid >> 6;
  const int lane = tid & 63;

  const int gz0 = tz * TILE - KSTEPS;
  const int gx0 = tx * TILE - KSTEPS;
  const int gx  = gx0 + lane;
  const int zb  = w * RPT;

  __shared__ float haloTop[2][NWAVES][64];
  __shared__ float haloBot[2][NWAVES][64];
  __shared__ float recTile[2][TILE][TILE + 1];
  __shared__ int   cntS;
  __shared__ int   lzA[NRECS], lxA[NRECS];
  __shared__ unsigned pkA[NRECS];

  // ---- prologue: receiver compaction + masks (as R5) ----
  if (tid == 0) cntS = 0;
  __syncthreads();
  if (tid < NRECS) {
    const int lz = rec_z[s * NRECS + tid] - tz * TILE;
    const int lx = rec_x[s * NRECS + tid] - tx * TILE;
    lzA[tid] = lz; lxA[tid] = lx;
    if ((unsigned)lz < (unsigned)TILE && (unsigned)lx < (unsigned)TILE) {
      const int k = atomicAdd(&cntS, 1);
      pkA[k] = (unsigned)tid | ((unsigned)lz << 8) | ((unsigned)lx << 16);
    }
  }
  __syncthreads();
  const int nRec = cntS;
  int myR = 0, myLz = 0, myLx = 0;
  if (tid < nRec) {
    const unsigned p = pkA[tid];
    myR = p & 255; myLz = (p >> 8) & 31; myLx = (p >> 16) & 31;
  }
  const bool wbRow = (w >= 2 && w < 6) && (lane >= KSTEPS && lane < KSTEPS + TILE);
  const int  ilz   = (w - 2) * RPT;
  const int  ilx   = lane - KSTEPS;
  unsigned recMask = 0;
  if (wbRow) {
    for (int r = 0; r < NRECS; ++r)
      if (lxA[r] == ilx && (unsigned)(lzA[r] - ilz) < (unsigned)RPT)
        recMask |= 1u << (lzA[r] - ilz);
  }

  // neighbor bid for flag lanes (tid<8 -> the 8 surrounding tiles, same shot)
  int nb = -1;
  if (tid < 8) {
    const int k  = (tid < 4) ? tid : tid + 1;   // skip center of 3x3
    const int dz = k / 3 - 1, dx = k % 3 - 1;
    const int qz = tz + dz, qx = tx + dx;
    if ((unsigned)qz < 8u && (unsigned)qx < 8u)
      nb = (s << 6) | (qz << 3) | qx;
  }
  unsigned* wF = bar;
  unsigned* rF = bar + (size_t)NWG * LSTRIDE;

  auto pollGE = [&](unsigned* base, unsigned target) {
    if (nb >= 0) {
      while (fload(base + (size_t)nb * LSTRIDE) < target)
        __builtin_amdgcn_s_sleep(1);
    }
  };

  // source mask, packed per row-pair
  const int slz = src_z[s] - gz0;
  const int slx = src_x[s] - gx0;
  const bool srcMine = (slx == lane) && ((unsigned)(slz - zb) < (unsigned)RPT);
  const int  srcI = slz - zb;
  v2f srcM2[NPAIRS];
  #pragma unroll
  for (int p = 0; p < NPAIRS; ++p) {
    srcM2[p].x = (srcMine && srcI == 2 * p)     ? 1.0f : 0.0f;
    srcM2[p].y = (srcMine && srcI == 2 * p + 1) ? 1.0f : 0.0f;
  }

  // phase-invariant per-row addresses/validity; c2 and d2=2-4c2 packed
  const bool xok = (unsigned)gx < (unsigned)NX;
  int   offRow[RPT];
  bool  okRow[RPT];
  v2f a2[NPAIRS], b2[NPAIRS], c22[NPAIRS], d22[NPAIRS];
  #pragma unroll
  for (int p = 0; p < NPAIRS; ++p) {
    #pragma unroll
    for (int h = 0; h < 2; ++h) {
      const int i  = 2 * p + h;
      const int gz = gz0 + zb + i;
      const bool ok = xok && ((unsigned)gz < (unsigned)NZ);
      okRow[i]  = ok;
      offRow[i] = ok ? ((s * NZ + gz) * NX + gx) : 0;
      float v = ok ? vp[gz * NX + gx] : 0.0f;
      v *= DTf;
      const float c2 = v * v * INVDH2;
      if (h == 0) { c22[p].x = c2; d22[p].x = 2.0f - 4.0f * c2; }
      else        { c22[p].y = c2; d22[p].y = 2.0f - 4.0f * c2; }
    }
    a2[p] = (v2f)(0.0f); b2[p] = (v2f)(0.0f);
  }

  #pragma unroll 1
  for (int ph = 0; ph < NPHASE; ++ph) {
    const int t0 = ph * KSTEPS;

    if (ph > 0) {
      pollGE(wF, (unsigned)ph);        // 8 neighbors finished phase ph-1
      __syncthreads();
      const float* rc = (ph & 1) ? f0c : f1c;
      const float* rp = (ph & 1) ? f0p : f1p;
      if (!wbRow) {                    // interior threads keep a,b in regs
        #pragma unroll
        for (int p = 0; p < NPAIRS; ++p) {
          a2[p].x = okRow[2 * p]     ? gload(rc + offRow[2 * p])     : 0.0f;
          a2[p].y = okRow[2 * p + 1] ? gload(rc + offRow[2 * p + 1]) : 0.0f;
          b2[p].x = okRow[2 * p]     ? gload(rp + offRow[2 * p])     : 0.0f;
          b2[p].y = okRow[2 * p + 1] ? gload(rp + offRow[2 * p + 1]) : 0.0f;
        }
      }
      __builtin_amdgcn_s_waitcnt(0);   // my reload actually read memory
      __syncthreads();
      if (tid == 0) fstore(rF + (size_t)bid * LSTRIDE, (unsigned)ph);
    }

    // 16 source amps via 4 vector loads
    float amp[KSTEPS];
    {
      const float4* xw4 = (const float4*)(xwav + s * NT + t0);
      #pragma unroll
      for (int q = 0; q < KSTEPS / 4; ++q) {
        const float4 v = xw4[q];
        amp[4 * q + 0] = (v.x * DTf) * DTf;
        amp[4 * q + 1] = (v.y * DTf) * DTf;
        amp[4 * q + 2] = (v.z * DTf) * DTf;
        amp[4 * q + 3] = (v.w * DTf) * DTf;
      }
    }

    float recv[KSTEPS];

    // one step, row-pair packed: p' = d2*c + c2*sum - prev (+ src)
    auto do_step = [&](v2f (&cur)[NPAIRS], v2f (&nxt)[NPAIRS], int tau) {
      const int pb = tau & 1;
      haloTop[pb][w][lane] = cur[0].x;
      haloBot[pb][w][lane] = cur[NPAIRS - 1].y;
      __syncthreads();
      if (tau > 0 && tid < nRec) recv[tau - 1] = recTile[1 - pb][myLz][myLx];
      const float up0 = (w > 0)          ? haloBot[pb][w - 1][lane] : 0.0f;
      const float dn7 = (w < NWAVES - 1) ? haloTop[pb][w + 1][lane] : 0.0f;
      const v2f av = { amp[tau], amp[tau] };
      #pragma unroll
      for (int p = 0; p < NPAIRS; ++p) {
        const float cx = cur[p].x, cy = cur[p].y;
        const float upx = (p == 0)          ? up0 : cur[p - 1].y;
        const float dny = (p == NPAIRS - 1) ? dn7 : cur[p + 1].x;
        v2f ud, lr;
        ud.x = upx + cy;                 // up(2p)+dn(2p)   (dn(2p)=cur[p].y)
        ud.y = cx + dny;                 // up(2p+1)+dn(2p+1) (up=cur[p].x)
        lr.x = nbr_left(cx) + nbr_right(cx);
        lr.y = nbr_left(cy) + nbr_right(cy);
        const v2f sum = ud + lr;                                   // pk_add
        v2f t = __builtin_elementwise_fma(c22[p], sum, -nxt[p]);   // pk_fma
        t = __builtin_elementwise_fma(d22[p], cur[p], t);          // pk_fma
        t = __builtin_elementwise_fma(srcM2[p], av, t);            // pk_fma
        nxt[p] = t;
      }
      if (recMask) {
        #pragma unroll
        for (int i = 0; i < RPT; ++i)
          if (recMask & (1u << i))
            recTile[pb][ilz + i][ilx] = (i & 1) ? nxt[i >> 1].y : nxt[i >> 1].x;
      }
    };

    #pragma unroll
    for (int h = 0; h < KSTEPS / 2; ++h) {
      do_step(a2, b2, 2 * h);
      do_step(b2, a2, 2 * h + 1);
    }

    // neighbors consumed the pair we're about to overwrite
    if (ph >= 2 && ph != NPHASE - 1) pollGE(rF, (unsigned)(ph - 1));
    __syncthreads();   // recTile[1] ready + overwrite permission WG-wide
    if (tid < nRec) recv[KSTEPS - 1] = recTile[1][myLz][myLx];

    // receiver flush (normal cached stores; read only after kernel end)
    if (tid < nRec) {
      #pragma unroll
      for (int t = 0; t < KSTEPS; ++t)
        out[(s * NT + (t0 + t)) * NRECS + myR] = recv[t];
    }

    if (ph != NPHASE - 1) {
      // interior writeback (LLC-coherent)
      float* wc = (ph & 1) ? f1c : f0c;
      float* wp = (ph & 1) ? f1p : f0p;
      if (wbRow) {
        #pragma unroll
        for (int p = 0; p < NPAIRS; ++p) {
          gstore(wc + offRow[2 * p],     a2[p].x);
          gstore(wc + offRow[2 * p + 1], a2[p].y);
          gstore(wp + offRow[2 * p],     b2[p].x);
          gstore(wp + offRow[2 * p + 1], b2[p].y);
        }
      }
      __builtin_amdgcn_s_waitcnt(0);   // stores ack'd at LLC (per wave)
      __syncthreads();                 // whole WG drained
      if (tid == 0) fstore(wF + (size_t)bid * LSTRIDE, (unsigned)(ph + 1));
    }
  }
}

extern "C" void kernel_launch(void* const* d_in, const int* in_sizes, int n_in,
                              void* d_out, int out_size, void* d_ws, size_t ws_size,
                              hipStream_t stream) {
  const float* x     = (const float*)d_in[0];
  const float* vp    = (const float*)d_in[1];
  const int*   src_z = (const int*)d_in[2];
  const int*   src_x = (const int*)d_in[3];
  const int*   rec_z = (const int*)d_in[4];
  const int*   rec_x = (const int*)d_in[5];
  float* out = (float*)d_out;

  float* ws = (float*)d_ws;
  const size_t F = (size_t)NSHOTS * NZ * NX;
  float* f0c = ws;
  float* f0p = ws + F;
  float* f1c = ws + 2 * F;
  float* f1p = ws + 3 * F;
  unsigned* bar = (unsigned*)(ws + 4 * F);

  // zero the p2p flags (wFlag + rFlag, 128B-strided)
  hipMemsetAsync(bar, 0, 2 * (size_t)NWG * LSTRIDE * sizeof(unsigned), stream);

  wave_pk<<<dim3(NWG), dim3(BLOCK), 0, stream>>>(
      f0c, f0p, f1c, f1p, vp, x, src_z, src_x, rec_z, rec_x, out, bar);
}